// Round 1
// baseline (869.326 us; speedup 1.0000x reference)
//
#include <hip/hip_runtime.h>
#include <math.h>

// Problem constants (fixed by reference setup_inputs)
#define NTOT 100
#define NQ   75
#define NP   25    // mh = m * n_support
#define CC   128
#define TT   8
#define VV   25
#define NCLS 5
#define NSUP 5
#define NQRY 15
#define ROW  (TT*VV*CC)   // 25600 floats per sample
#define TILE (VV*CC)      // 3200 floats per (n,t)

// ---------- kernel 1: stable-sort ranks -> source indices ----------
__global__ void k_build_src(const int* __restrict__ target, int* __restrict__ src_idx) {
    __shared__ int order[NTOT];
    int i = threadIdx.x;
    if (i < NTOT) {
        int ti = target[i];
        int rank = 0;
        for (int j = 0; j < NTOT; ++j) {
            int tj = target[j];
            rank += (tj < ti) || (tj == ti && j < i);
        }
        order[rank] = i;
    }
    __syncthreads();
    if (i < NQ) {
        int m = i / NQRY, q = i - m * NQRY;
        src_idx[i] = order[m * (NSUP + NQRY) + NSUP + q];
    }
    if (i < NP) {
        int m = i / NSUP, s = i - m * NSUP;
        src_idx[NQ + i] = order[m * (NSUP + NQRY) + s];
    }
}

// ---------- kernel 2: gather + transpose (n,c,t,v) -> catX[n][t][v][c] ----------
__global__ void k_make_cat(const float* __restrict__ input, const int* __restrict__ src_idx,
                           float* __restrict__ catX) {
    int n = blockIdx.x;
    int src = src_idx[n];
    const float* in = input + (size_t)src * ROW;
    float* out = catX + (size_t)n * ROW;
    for (int e = threadIdx.x; e < ROW; e += blockDim.x) {
        int c = e & (CC - 1);
        int tv = e >> 7;
        int t = tv / VV;
        int v = tv - t * VV;
        out[e] = in[c * (TT * VV) + t * VV + v];   // coalesced write, strided read (L2-resident)
    }
}

// ---------- kernel 3: C[M x 128] = A[M x 128] @ W[128 x 128] (+bias) ----------
__global__ __launch_bounds__(256) void k_gemm128(const float* __restrict__ A,
        const float* __restrict__ W, const float* __restrict__ bias,
        float* __restrict__ Cout, int M) {
    __shared__ float As[64][17];    // pad 17: broadcast rows land in distinct banks
    __shared__ float Ws[16][132];
    int tid = threadIdx.x;
    int rg = tid >> 5, cg = tid & 31;
    int row0 = blockIdx.x * 64;
    float4 acc[8];
    #pragma unroll
    for (int i = 0; i < 8; ++i) acc[i] = make_float4(0.f, 0.f, 0.f, 0.f);

    for (int kc = 0; kc < 8; ++kc) {
        int k0 = kc * 16;
        for (int idx = tid; idx < 1024; idx += 256) {
            int r = idx >> 4, kk = idx & 15;
            int row = row0 + r;
            As[r][kk] = (row < M) ? A[(size_t)row * CC + k0 + kk] : 0.f;
        }
        for (int idx = tid; idx < 2048; idx += 256) {
            int r = idx >> 7, c = idx & 127;
            Ws[r][c] = W[(k0 + r) * CC + c];
        }
        __syncthreads();
        #pragma unroll
        for (int kk = 0; kk < 16; ++kk) {
            float4 w4 = *(const float4*)&Ws[kk][cg * 4];
            #pragma unroll
            for (int i = 0; i < 8; ++i) {
                float a = As[rg * 8 + i][kk];
                acc[i].x += a * w4.x; acc[i].y += a * w4.y;
                acc[i].z += a * w4.z; acc[i].w += a * w4.w;
            }
        }
        __syncthreads();
    }
    float4 b4 = make_float4(0.f, 0.f, 0.f, 0.f);
    if (bias) b4 = *(const float4*)&bias[cg * 4];
    #pragma unroll
    for (int i = 0; i < 8; ++i) {
        int row = row0 + rg * 8 + i;
        if (row < M) {
            float4 o;
            o.x = acc[i].x + b4.x; o.y = acc[i].y + b4.y;
            o.z = acc[i].z + b4.z; o.w = acc[i].w + b4.w;
            *(float4*)&Cout[(size_t)row * CC + cg * 4] = o;
        }
    }
}

// ---------- kernel 4: fused attention + residual + LN + mean over m ----------
// block per (n,t); Wo pre-folded into Vo so ctx@Wo == P@Vo.
__global__ __launch_bounds__(256) void k_attn(const float* __restrict__ Q,
        const float* __restrict__ Kb, const float* __restrict__ Vo,
        const float* __restrict__ catX, const float* __restrict__ bo,
        const float* __restrict__ ln_g, const float* __restrict__ ln_b,
        float* __restrict__ att) {
    __shared__ float Qs[25][132];
    __shared__ float Cs[25][132];
    __shared__ float Ks[25][132];
    __shared__ float Vos[25][132];
    __shared__ float Sm[25][27];    // stride 27: q-groups {q,q+8,q+16,q+24} hit distinct banks
    __shared__ float bos[128], gs[128], bs[128];

    int bid = blockIdx.x;
    int n = bid >> 3;
    int t = bid & 7;
    int tid = threadIdx.x;
    const float scale = 0.08838834764831845f;  // 1/sqrt(128)

    size_t baseQ = ((size_t)n * TT + t) * TILE;
    for (int idx = tid; idx < TILE; idx += 256) {
        int q = idx >> 7, c = idx & 127;
        Qs[q][c] = Q[baseQ + idx];
        Cs[q][c] = catX[baseQ + idx];
    }
    if (tid < 128) { bos[tid] = bo[tid]; gs[tid] = ln_g[tid]; bs[tid] = ln_b[tid]; }

    int qg = tid >> 5, cg = tid & 31;
    int nq = (qg == 0) ? 4 : 3;       // q rows owned: qg, qg+8, qg+16 (+24 for qg==0)
    float4 acc4[4];
    #pragma unroll
    for (int i = 0; i < 4; ++i) acc4[i] = make_float4(0.f, 0.f, 0.f, 0.f);

    int sq = tid >> 3, skg = tid & 7;

    for (int m = 0; m < NP; ++m) {
        __syncthreads();   // protect Ks/Vos from previous-iteration readers
        size_t baseK = ((size_t)m * TT + t) * TILE;
        for (int idx = tid; idx < TILE; idx += 256) {
            int q = idx >> 7, c = idx & 127;
            Ks[q][c]  = Kb[baseK + idx];
            Vos[q][c] = Vo[baseK + idx];
        }
        __syncthreads();

        // ---- scores S[q][k] = (Q[q] . K[k]) * scale ----
        if (sq < 25) {
            const float4* qrow = (const float4*)&Qs[sq][0];
            for (int k = skg; k < 25; k += 8) {
                const float4* krow = (const float4*)&Ks[k][0];
                float s = 0.f;
                #pragma unroll
                for (int c4 = 0; c4 < 32; ++c4) {
                    float4 a = qrow[c4], b = krow[c4];
                    s += a.x*b.x + a.y*b.y + a.z*b.z + a.w*b.w;
                }
                Sm[sq][k] = s * scale;
            }
        }
        __syncthreads();

        // ---- softmax over k per row ----
        if (tid < 25) {
            float mx = Sm[tid][0];
            for (int k = 1; k < 25; ++k) mx = fmaxf(mx, Sm[tid][k]);
            float sum = 0.f;
            for (int k = 0; k < 25; ++k) sum += expf(Sm[tid][k] - mx);
            float inv = 1.f / sum;
            for (int k = 0; k < 25; ++k) Sm[tid][k] = expf(Sm[tid][k] - mx) * inv;
        }
        __syncthreads();

        // ---- ctx = P @ Vo, + bo + cat, LayerNorm, accumulate ----
        float4 ctx[4];
        #pragma unroll
        for (int i = 0; i < 4; ++i) ctx[i] = make_float4(0.f, 0.f, 0.f, 0.f);
        for (int k = 0; k < 25; ++k) {
            float4 v4 = *(const float4*)&Vos[k][cg * 4];
            #pragma unroll
            for (int qi = 0; qi < 4; ++qi) {
                if (qi < nq) {
                    float p = Sm[qg + 8 * qi][k];
                    ctx[qi].x += p * v4.x; ctx[qi].y += p * v4.y;
                    ctx[qi].z += p * v4.z; ctx[qi].w += p * v4.w;
                }
            }
        }
        float4 b4  = *(const float4*)&bos[cg * 4];
        float4 g4  = *(const float4*)&gs[cg * 4];
        float4 bb4 = *(const float4*)&bs[cg * 4];
        #pragma unroll
        for (int qi = 0; qi < 4; ++qi) {
            if (qi < nq) {
                int q = qg + 8 * qi;
                float4 cat4 = *(const float4*)&Cs[q][cg * 4];
                float4 x;
                x.x = ctx[qi].x + b4.x + cat4.x;
                x.y = ctx[qi].y + b4.y + cat4.y;
                x.z = ctx[qi].z + b4.z + cat4.z;
                x.w = ctx[qi].w + b4.w + cat4.w;
                float s1 = x.x + x.y + x.z + x.w;
                float s2 = x.x*x.x + x.y*x.y + x.z*x.z + x.w*x.w;
                #pragma unroll
                for (int msk = 16; msk >= 1; msk >>= 1) {
                    s1 += __shfl_xor(s1, msk);   // 32-lane groups align with cg
                    s2 += __shfl_xor(s2, msk);
                }
                float mu  = s1 * (1.f / 128.f);
                float var = s2 * (1.f / 128.f) - mu * mu;
                var = fmaxf(var, 0.f);
                float rs = rsqrtf(var + 1e-12f);
                acc4[qi].x += (x.x - mu) * rs * g4.x + bb4.x;
                acc4[qi].y += (x.y - mu) * rs * g4.y + bb4.y;
                acc4[qi].z += (x.z - mu) * rs * g4.z + bb4.z;
                acc4[qi].w += (x.w - mu) * rs * g4.w + bb4.w;
            }
        }
    }

    // write mean over m (1/25)
    #pragma unroll
    for (int qi = 0; qi < 4; ++qi) {
        if (qi < nq) {
            int q = qg + 8 * qi;
            float4 o;
            o.x = acc4[qi].x * 0.04f; o.y = acc4[qi].y * 0.04f;
            o.z = acc4[qi].z * 0.04f; o.w = acc4[qi].w * 0.04f;
            *(float4*)&att[baseQ + q * CC + cg * 4] = o;
        }
    }
}

// ---------- kernel 5: class prototypes = mean over supports ----------
__global__ void k_proto(const float* __restrict__ att, float* __restrict__ proto) {
    int cls = blockIdx.x;
    const float* a0 = att + (size_t)(NQ + cls * NSUP) * ROW;
    float* p = proto + (size_t)cls * ROW;
    for (int e = threadIdx.x; e < ROW; e += blockDim.x) {
        float s = 0.f;
        #pragma unroll
        for (int j = 0; j < NSUP; ++j) s += a0[(size_t)j * ROW + e];
        p[e] = s * 0.2f;
    }
}

// ---------- kernel 6: squared distances (75 x 5) ----------
__global__ __launch_bounds__(256) void k_dist(const float* __restrict__ att,
        const float* __restrict__ proto, float* __restrict__ dist) {
    int i = blockIdx.x;
    const float* a = att + (size_t)i * ROW;
    float d[5] = {0.f, 0.f, 0.f, 0.f, 0.f};
    for (int e = threadIdx.x; e < ROW; e += 256) {
        float av = a[e];
        #pragma unroll
        for (int j = 0; j < 5; ++j) {
            float diff = av - proto[(size_t)j * ROW + e];
            d[j] += diff * diff;
        }
    }
    __shared__ float part[4][5];
    int lane = threadIdx.x & 63, wv = threadIdx.x >> 6;
    #pragma unroll
    for (int j = 0; j < 5; ++j) {
        #pragma unroll
        for (int msk = 32; msk >= 1; msk >>= 1) d[j] += __shfl_xor(d[j], msk);
    }
    if (lane == 0) {
        #pragma unroll
        for (int j = 0; j < 5; ++j) part[wv][j] = d[j];
    }
    __syncthreads();
    if (threadIdx.x < 5) {
        dist[i * 5 + threadIdx.x] = part[0][threadIdx.x] + part[1][threadIdx.x]
                                  + part[2][threadIdx.x] + part[3][threadIdx.x];
    }
}

// ---------- kernel 7: log-softmax loss + accuracy ----------
__global__ void k_loss(const float* __restrict__ dist, float* __restrict__ out) {
    int i = threadIdx.x;   // 128 threads, 75 active
    float li = 0.f, ok = 0.f;
    if (i < NQ) {
        float dd[5];
        #pragma unroll
        for (int j = 0; j < 5; ++j) dd[j] = dist[i * 5 + j];
        int cls = i / NQRY;
        float mind = dd[0];
        int best = 0;
        #pragma unroll
        for (int j = 1; j < 5; ++j) {
            if (dd[j] < mind) mind = dd[j];
            if (dd[j] < dd[best]) best = j;   // first-min == jnp.argmax of -d
        }
        float sume = 0.f;
        #pragma unroll
        for (int j = 0; j < 5; ++j) sume += expf(mind - dd[j]);
        float lse = logf(sume) - mind;        // logsumexp(-d)
        li = dd[cls] + lse;                    // -log_p[cls]
        ok = (best == cls) ? 1.f : 0.f;
    }
    #pragma unroll
    for (int msk = 32; msk >= 1; msk >>= 1) {
        li += __shfl_xor(li, msk);
        ok += __shfl_xor(ok, msk);
    }
    __shared__ float pl[2], po[2];
    int wv = i >> 6, lane = i & 63;
    if (lane == 0) { pl[wv] = li; po[wv] = ok; }
    __syncthreads();
    if (i == 0) {
        out[0] = (pl[0] + pl[1]) / 75.f;
        out[1] = (po[0] + po[1]) / 75.f;
    }
}

extern "C" void kernel_launch(void* const* d_in, const int* in_sizes, int n_in,
                              void* d_out, int out_size, void* d_ws, size_t ws_size,
                              hipStream_t stream) {
    const float* input = (const float*)d_in[0];
    const float* Wq   = (const float*)d_in[1];
    const float* bq   = (const float*)d_in[2];
    const float* Wk   = (const float*)d_in[3];
    const float* bk   = (const float*)d_in[4];
    const float* Wv   = (const float*)d_in[5];
    const float* bv   = (const float*)d_in[6];
    const float* Wo   = (const float*)d_in[7];
    const float* bo   = (const float*)d_in[8];
    const float* ln_g = (const float*)d_in[9];
    const float* ln_b = (const float*)d_in[10];
    const int* target = (const int*)d_in[11];
    float* out = (float*)d_out;

    float* ws = (float*)d_ws;
    int* src_idx  = (int*)ws;                 // 100 ints (256 floats reserved)
    float* catX   = ws + 256;                 // 100*25600
    float* Qb     = catX + 2560000;           // 100*25600
    float* Kb     = Qb + 2560000;             // 25*8*25*128 = 640000
    float* Vt     = Kb + 640000;
    float* Vob    = Vt + 640000;
    float* attb   = Vob + 640000;             // 100*25600
    float* proto  = attb + 2560000;           // 5*25600
    float* distb  = proto + 128000;           // 375
    // total ~38.9 MB of workspace

    k_build_src<<<1, 128, 0, stream>>>(target, src_idx);
    k_make_cat<<<NTOT, 256, 0, stream>>>(input, src_idx, catX);
    // projections (Wo folded into V: Vo = (zp@Wv+bv)@Wo)
    k_gemm128<<<(NTOT * TT * VV + 63) / 64, 256, 0, stream>>>(catX, Wq, bq, Qb, NTOT * TT * VV);
    k_gemm128<<<(NP * TT * VV + 63) / 64, 256, 0, stream>>>(catX + (size_t)NQ * ROW, Wk, bk, Kb, NP * TT * VV);
    k_gemm128<<<(NP * TT * VV + 63) / 64, 256, 0, stream>>>(catX + (size_t)NQ * ROW, Wv, bv, Vt, NP * TT * VV);
    k_gemm128<<<(NP * TT * VV + 63) / 64, 256, 0, stream>>>(Vt, Wo, nullptr, Vob, NP * TT * VV);
    // fused attention + LN + mean over m
    k_attn<<<NTOT * TT, 256, 0, stream>>>(Qb, Kb, Vob, catX, bo, ln_g, ln_b, attb);
    // prototype mean, distances, loss/acc
    k_proto<<<NCLS, 256, 0, stream>>>(attb, proto);
    k_dist<<<NQ, 256, 0, stream>>>(attb, proto, distb);
    k_loss<<<1, 128, 0, stream>>>(distb, out);
}

// Round 2
// 360.575 us; speedup vs baseline: 2.4109x; 2.4109x over previous
//
#include <hip/hip_runtime.h>
#include <math.h>

// Problem constants (fixed by reference setup_inputs)
#define NTOT 100
#define NQ   75
#define NP   25
#define CC   128
#define TT   8
#define VV   25
#define NCLS 5
#define NSUP 5
#define NQRY 15
#define ROW  (TT*VV*CC)   // 25600 floats per sample
#define TILE (VV*CC)      // 3200 floats per (n,t)

typedef __attribute__((ext_vector_type(8))) short short8;
typedef __attribute__((ext_vector_type(16))) float f32x16;

__device__ __forceinline__ ushort f2bf(float f) {
    uint u = __float_as_uint(f);
    u += 0x7FFFu + ((u >> 16) & 1u);   // RNE
    return (ushort)(u >> 16);
}

// ---------- kernel 1: stable-sort ranks -> source indices ----------
__global__ void k_build_src(const int* __restrict__ target, int* __restrict__ src_idx) {
    __shared__ int order[NTOT];
    int i = threadIdx.x;
    if (i < NTOT) {
        int ti = target[i];
        int rank = 0;
        for (int j = 0; j < NTOT; ++j) {
            int tj = target[j];
            rank += (tj < ti) || (tj == ti && j < i);
        }
        order[rank] = i;
    }
    __syncthreads();
    if (i < NQ) {
        int m = i / NQRY, q = i - m * NQRY;
        src_idx[i] = order[m * (NSUP + NQRY) + NSUP + q];
    }
    if (i < NP) {
        int m = i / NSUP, s = i - m * NSUP;
        src_idx[NQ + i] = order[m * (NSUP + NQRY) + s];
    }
}

// ---------- kernel 2: gather + transpose (n,c,t,v) -> catX[n][t][v][c] ----------
__global__ void k_make_cat(const float* __restrict__ input, const int* __restrict__ src_idx,
                           float* __restrict__ catX) {
    int n = blockIdx.x;
    int src = src_idx[n];
    const float* in = input + (size_t)src * ROW;
    float* out = catX + (size_t)n * ROW;
    for (int e = threadIdx.x; e < ROW; e += blockDim.x) {
        int c = e & (CC - 1);
        int tv = e >> 7;
        int t = tv / VV;
        int v = tv - t * VV;
        out[e] = in[c * (TT * VV) + t * VV + v];
    }
}

// ---------- kernel 3: Wvo = Wv @ Wo ; bvo = bv @ Wo ----------
__global__ void k_prep_wvo(const float* __restrict__ Wv, const float* __restrict__ bv,
                           const float* __restrict__ Wo, float* __restrict__ Wvo,
                           float* __restrict__ bvo) {
    int r = blockIdx.x, c = threadIdx.x;  // 129 blocks x 128 threads
    if (r < 128) {
        float s = 0.f;
        for (int k = 0; k < 128; ++k) s += Wv[r * 128 + k] * Wo[k * 128 + c];
        Wvo[r * 128 + c] = s;
    } else {
        float s = 0.f;
        for (int k = 0; k < 128; ++k) s += bv[k] * Wo[k * 128 + c];
        bvo[c] = s;
    }
}

// ---------- GEMM core: C[M x 128] = A[M x 128] @ W[128 x 128] (+bias) ----------
// Epilogue writes bf16 MFMA fragments to global (see frag layouts in k_attn_mfma).
// Frag index maps (32x32x16 bf16):
//   A/B-frag: lane l holds elem[row = l&31][k = (l>>5)*8 + j], j=0..7
//   QK frag layout: [st = row/25][kstep=c>>4][lane = v + 32*((c>>3)&1)][j = c&7]
//   VO frag layout (A = Vo^T): [mt8][mtile=c>>5][kstep=v>>4][lane=(c&31)+32*((v&15)>>3)][j=v&7]
__global__ __launch_bounds__(256) void k_gemm_qk(const float* __restrict__ A,
        const float* __restrict__ W, const float* __restrict__ bias,
        ushort* __restrict__ outU, int M) {
    __shared__ float As[64][17];
    __shared__ float Ws[16][132];
    int tid = threadIdx.x;
    int rg = tid >> 5, cg = tid & 31;
    int row0 = blockIdx.x * 64;
    float4 acc[8];
    #pragma unroll
    for (int i = 0; i < 8; ++i) acc[i] = make_float4(0.f, 0.f, 0.f, 0.f);

    for (int kc = 0; kc < 8; ++kc) {
        int k0 = kc * 16;
        for (int idx = tid; idx < 1024; idx += 256) {
            int r = idx >> 4, kk = idx & 15;
            int row = row0 + r;
            As[r][kk] = (row < M) ? A[(size_t)row * CC + k0 + kk] : 0.f;
        }
        for (int idx = tid; idx < 2048; idx += 256) {
            int r = idx >> 7, c = idx & 127;
            Ws[r][c] = W[(k0 + r) * CC + c];
        }
        __syncthreads();
        #pragma unroll
        for (int kk = 0; kk < 16; ++kk) {
            float4 w4 = *(const float4*)&Ws[kk][cg * 4];
            #pragma unroll
            for (int i = 0; i < 8; ++i) {
                float a = As[rg * 8 + i][kk];
                acc[i].x += a * w4.x; acc[i].y += a * w4.y;
                acc[i].z += a * w4.z; acc[i].w += a * w4.w;
            }
        }
        __syncthreads();
    }
    float4 b4 = *(const float4*)&bias[cg * 4];
    int c0 = cg * 4;
    int ks = c0 >> 4, hf = (c0 >> 3) & 1, j0 = c0 & 7;
    #pragma unroll
    for (int i = 0; i < 8; ++i) {
        int row = row0 + rg * 8 + i;
        if (row < M) {
            float ox = acc[i].x + b4.x, oy = acc[i].y + b4.y;
            float oz = acc[i].z + b4.z, ow = acc[i].w + b4.w;
            int v = row % 25, st = row / 25;
            uint2 pk;
            pk.x = (uint)f2bf(ox) | ((uint)f2bf(oy) << 16);
            pk.y = (uint)f2bf(oz) | ((uint)f2bf(ow) << 16);
            size_t dst = (((size_t)st * 8 + ks) * 64 + (v + 32 * hf)) * 8 + j0;
            *(uint2*)(outU + dst) = pk;
        }
    }
}

__global__ __launch_bounds__(256) void k_gemm_vo(const float* __restrict__ A,
        const float* __restrict__ W, const float* __restrict__ bias,
        ushort* __restrict__ outU, int M) {
    __shared__ float As[64][17];
    __shared__ float Ws[16][132];
    int tid = threadIdx.x;
    int rg = tid >> 5, cg = tid & 31;
    int row0 = blockIdx.x * 64;
    float4 acc[8];
    #pragma unroll
    for (int i = 0; i < 8; ++i) acc[i] = make_float4(0.f, 0.f, 0.f, 0.f);

    for (int kc = 0; kc < 8; ++kc) {
        int k0 = kc * 16;
        for (int idx = tid; idx < 1024; idx += 256) {
            int r = idx >> 4, kk = idx & 15;
            int row = row0 + r;
            As[r][kk] = (row < M) ? A[(size_t)row * CC + k0 + kk] : 0.f;
        }
        for (int idx = tid; idx < 2048; idx += 256) {
            int r = idx >> 7, c = idx & 127;
            Ws[r][c] = W[(k0 + r) * CC + c];
        }
        __syncthreads();
        #pragma unroll
        for (int kk = 0; kk < 16; ++kk) {
            float4 w4 = *(const float4*)&Ws[kk][cg * 4];
            #pragma unroll
            for (int i = 0; i < 8; ++i) {
                float a = As[rg * 8 + i][kk];
                acc[i].x += a * w4.x; acc[i].y += a * w4.y;
                acc[i].z += a * w4.z; acc[i].w += a * w4.w;
            }
        }
        __syncthreads();
    }
    float4 b4 = *(const float4*)&bias[cg * 4];
    #pragma unroll
    for (int i = 0; i < 8; ++i) {
        int row = row0 + rg * 8 + i;
        if (row < M) {
            float vals[4];
            vals[0] = acc[i].x + b4.x; vals[1] = acc[i].y + b4.y;
            vals[2] = acc[i].z + b4.z; vals[3] = acc[i].w + b4.w;
            int v = row % 25, mt8 = row / 25;
            int ks = v >> 4, hf = (v & 15) >> 3, j = v & 7;
            #pragma unroll
            for (int cc = 0; cc < 4; ++cc) {
                int c = cg * 4 + cc;
                int mt = c >> 5, ln = (c & 31) + 32 * hf;
                size_t dst = ((((size_t)mt8 * 4 + mt) * 2 + ks) * 64 + ln) * 8 + j;
                outU[dst] = f2bf(vals[cc]);
            }
        }
    }
}

// ---------- kernel 4: MFMA fused attention + residual + LN + mean over m ----------
// block per (n,t); 4 waves split m (stride 4); no barriers in m-loop.
// S^T = K . Q^T  (D[key][q]): softmax over keys = in-lane (16 regs) + shfl_xor(32).
// ctx^T = Vo^T . P^T (D[c][q]): LN over channels = in-lane 64 + shfl_xor(32).
__global__ __launch_bounds__(256, 2) void k_attn_mfma(
    const ushort* __restrict__ Qf, const ushort* __restrict__ Kf,
    const ushort* __restrict__ Vf, const float* __restrict__ catX,
    const float* __restrict__ bo, const float* __restrict__ ln_g,
    const float* __restrict__ ln_b, float* __restrict__ att) {
    __shared__ float catb[25][132];
    __shared__ float gb[2][128];
    __shared__ ushort pfrag[4][2][64][8];   // per-wave B-frag scratch for P^T
    __shared__ float red[64][68];

    int bid = blockIdx.x;          // n*8 + t
    int t = bid & 7;
    int tid = threadIdx.x;
    int wv = tid >> 6, lane = tid & 63;
    int q = lane & 31, half = lane >> 5;

    size_t base = (size_t)bid * TILE;
    for (int idx = tid; idx < TILE; idx += 256) {
        int qq = idx >> 7, c = idx & 127;
        catb[qq][c] = catX[base + idx] + bo[c];   // residual + bo pre-added
    }
    if (tid < 128) { gb[0][tid] = ln_g[tid]; gb[1][tid] = ln_b[tid]; }

    short8 qf[8];
    {
        const ushort* qp = Qf + (size_t)bid * 4096 + lane * 8;
        #pragma unroll
        for (int ks = 0; ks < 8; ++ks) qf[ks] = *(const short8*)(qp + ks * 512);
    }
    __syncthreads();

    int qc = q < 25 ? q : 24;   // clamp garbage q-lanes for LDS reads
    float attsum[64];
    #pragma unroll
    for (int i = 0; i < 64; ++i) attsum[i] = 0.f;

    const float CEXP = (float)(1.4426950408889634 * 0.08838834764831845); // log2e/sqrt(128)

    for (int m = wv; m < 25; m += 4) {
        // --- K frags straight from global (coalesced dwordx4, no LDS) ---
        const ushort* kp = Kf + ((size_t)(m * 8 + t)) * 4096 + lane * 8;
        short8 kf[8];
        #pragma unroll
        for (int ks = 0; ks < 8; ++ks) kf[ks] = *(const short8*)(kp + ks * 512);
        f32x16 S;
        #pragma unroll
        for (int r = 0; r < 16; ++r) S[r] = 0.f;
        #pragma unroll
        for (int ks = 0; ks < 8; ++ks)
            S = __builtin_amdgcn_mfma_f32_32x32x16_bf16(kf[ks], qf[ks], S, 0, 0, 0);

        // --- softmax over keys (rows of S^T: in-lane + pair shuffle) ---
        float p[16], mx = -3e38f;
        #pragma unroll
        for (int r = 0; r < 16; ++r) {
            int key = (r & 3) + 8 * (r >> 2) + 4 * half;
            float v = (key < 25) ? S[r] : -3e38f;
            p[r] = v; mx = fmaxf(mx, v);
        }
        mx = fmaxf(mx, __shfl_xor(mx, 32));
        float sum = 0.f;
        #pragma unroll
        for (int r = 0; r < 16; ++r) { p[r] = exp2f((p[r] - mx) * CEXP); sum += p[r]; }
        sum += __shfl_xor(sum, 32);
        float inv = 1.f / sum;

        // --- P^T (C-layout) -> B-frag via wave-private LDS roundtrip ---
        #pragma unroll
        for (int r = 0; r < 16; ++r) {
            int key = (r & 3) + 8 * (r >> 2) + 4 * half;
            pfrag[wv][key >> 4][q + 32 * ((key >> 3) & 1)][key & 7] = f2bf(p[r] * inv);
        }
        short8 pb0 = *(const short8*)&pfrag[wv][0][lane][0];
        short8 pb1 = *(const short8*)&pfrag[wv][1][lane][0];

        // --- ctx^T = Vo^T . P^T : 4 mtiles x 2 ksteps ---
        const ushort* vp = Vf + ((size_t)(m * 8 + t)) * 4096 + lane * 8;
        f32x16 ctx[4];
        #pragma unroll
        for (int mt = 0; mt < 4; ++mt) {
            short8 v0 = *(const short8*)(vp + mt * 1024);
            short8 v1 = *(const short8*)(vp + mt * 1024 + 512);
            f32x16 c;
            #pragma unroll
            for (int r = 0; r < 16; ++r) c[r] = 0.f;
            c = __builtin_amdgcn_mfma_f32_32x32x16_bf16(v0, pb0, c, 0, 0, 0);
            c = __builtin_amdgcn_mfma_f32_32x32x16_bf16(v1, pb1, c, 0, 0, 0);
            ctx[mt] = c;
        }

        // --- x = ctx + (cat + bo); LN (in-lane + pair shuffle); accumulate ---
        float s1 = 0.f, s2 = 0.f;
        #pragma unroll
        for (int mt = 0; mt < 4; ++mt) {
            #pragma unroll
            for (int r = 0; r < 16; ++r) {
                int c = mt * 32 + (r & 3) + 8 * (r >> 2) + 4 * half;
                float xv = ctx[mt][r] + catb[qc][c];
                ctx[mt][r] = xv;
                s1 += xv; s2 += xv * xv;
            }
        }
        s1 += __shfl_xor(s1, 32); s2 += __shfl_xor(s2, 32);
        float mu = s1 * (1.f / 128.f);
        float var = s2 * (1.f / 128.f) - mu * mu;
        var = fmaxf(var, 0.f);
        float rs = rsqrtf(var + 1e-12f);
        #pragma unroll
        for (int mt = 0; mt < 4; ++mt) {
            #pragma unroll
            for (int r = 0; r < 16; ++r)
                attsum[mt * 16 + r] += (ctx[mt][r] - mu) * rs;   // g,b applied once at end
        }
    }

    // --- cross-wave reduction of attsum, then scale + affine + store ---
    __syncthreads();
    if (wv == 0) {
        #pragma unroll
        for (int i = 0; i < 64; ++i) red[lane][i] = attsum[i];
    }
    __syncthreads();
    if (wv == 1) {
        #pragma unroll
        for (int i = 0; i < 64; ++i) red[lane][i] += attsum[i];
    }
    __syncthreads();
    if (wv == 2) {
        #pragma unroll
        for (int i = 0; i < 64; ++i) red[lane][i] += attsum[i];
    }
    __syncthreads();
    if (wv == 3 && q < 25) {
        #pragma unroll
        for (int mt = 0; mt < 4; ++mt) {
            #pragma unroll
            for (int r = 0; r < 16; ++r) {
                int c = mt * 32 + (r & 3) + 8 * (r >> 2) + 4 * half;
                float v = (red[lane][mt * 16 + r] + attsum[mt * 16 + r]) * 0.04f;
                att[base + q * 128 + c] = v * gb[0][c] + gb[1][c];
            }
        }
    }
}

// ---------- kernel 5: class prototypes = mean over supports ----------
__global__ void k_proto(const float* __restrict__ att, float* __restrict__ proto) {
    int cls = blockIdx.x;
    const float* a0 = att + (size_t)(NQ + cls * NSUP) * ROW;
    float* p = proto + (size_t)cls * ROW;
    for (int e = threadIdx.x; e < ROW; e += blockDim.x) {
        float s = 0.f;
        #pragma unroll
        for (int j = 0; j < NSUP; ++j) s += a0[(size_t)j * ROW + e];
        p[e] = s * 0.2f;
    }
}

// ---------- kernel 6: squared distances (75 x 5) ----------
__global__ __launch_bounds__(256) void k_dist(const float* __restrict__ att,
        const float* __restrict__ proto, float* __restrict__ dist) {
    int i = blockIdx.x;
    const float* a = att + (size_t)i * ROW;
    float d[5] = {0.f, 0.f, 0.f, 0.f, 0.f};
    for (int e = threadIdx.x; e < ROW; e += 256) {
        float av = a[e];
        #pragma unroll
        for (int j = 0; j < 5; ++j) {
            float diff = av - proto[(size_t)j * ROW + e];
            d[j] += diff * diff;
        }
    }
    __shared__ float part[4][5];
    int lane = threadIdx.x & 63, wv = threadIdx.x >> 6;
    #pragma unroll
    for (int j = 0; j < 5; ++j) {
        #pragma unroll
        for (int msk = 32; msk >= 1; msk >>= 1) d[j] += __shfl_xor(d[j], msk);
    }
    if (lane == 0) {
        #pragma unroll
        for (int j = 0; j < 5; ++j) part[wv][j] = d[j];
    }
    __syncthreads();
    if (threadIdx.x < 5) {
        dist[i * 5 + threadIdx.x] = part[0][threadIdx.x] + part[1][threadIdx.x]
                                  + part[2][threadIdx.x] + part[3][threadIdx.x];
    }
}

// ---------- kernel 7: log-softmax loss + accuracy ----------
__global__ void k_loss(const float* __restrict__ dist, float* __restrict__ out) {
    int i = threadIdx.x;
    float li = 0.f, ok = 0.f;
    if (i < NQ) {
        float dd[5];
        #pragma unroll
        for (int j = 0; j < 5; ++j) dd[j] = dist[i * 5 + j];
        int cls = i / NQRY;
        float mind = dd[0];
        int best = 0;
        #pragma unroll
        for (int j = 1; j < 5; ++j) {
            if (dd[j] < mind) mind = dd[j];
            if (dd[j] < dd[best]) best = j;
        }
        float sume = 0.f;
        #pragma unroll
        for (int j = 0; j < 5; ++j) sume += expf(mind - dd[j]);
        float lse = logf(sume) - mind;
        li = dd[cls] + lse;
        ok = (best == cls) ? 1.f : 0.f;
    }
    #pragma unroll
    for (int msk = 32; msk >= 1; msk >>= 1) {
        li += __shfl_xor(li, msk);
        ok += __shfl_xor(ok, msk);
    }
    __shared__ float pl[2], po[2];
    int wv = i >> 6, lane = i & 63;
    if (lane == 0) { pl[wv] = li; po[wv] = ok; }
    __syncthreads();
    if (i == 0) {
        out[0] = (pl[0] + pl[1]) / 75.f;
        out[1] = (po[0] + po[1]) / 75.f;
    }
}

extern "C" void kernel_launch(void* const* d_in, const int* in_sizes, int n_in,
                              void* d_out, int out_size, void* d_ws, size_t ws_size,
                              hipStream_t stream) {
    const float* input = (const float*)d_in[0];
    const float* Wq   = (const float*)d_in[1];
    const float* bq   = (const float*)d_in[2];
    const float* Wk   = (const float*)d_in[3];
    const float* bk   = (const float*)d_in[4];
    const float* Wv   = (const float*)d_in[5];
    const float* bv   = (const float*)d_in[6];
    const float* Wo   = (const float*)d_in[7];
    const float* bo   = (const float*)d_in[8];
    const float* ln_g = (const float*)d_in[9];
    const float* ln_b = (const float*)d_in[10];
    const int* target = (const int*)d_in[11];
    float* out = (float*)d_out;

    float* ws = (float*)d_ws;
    int*    src_idx = (int*)ws;                 // 256 floats reserved
    float*  catX = ws + 256;                    // 100*25600
    float*  Wvo  = catX + 2560000;              // 16384
    float*  bvo  = Wvo + 16384;                 // 128
    ushort* Qf   = (ushort*)(bvo + 128);        // 100*8*4096 = 3,276,800 ushort
    ushort* Kf   = Qf + 3276800;                // 25*8*4096  =   819,200
    ushort* Vf   = Kf + 819200;                 //   819,200
    float*  attb = (float*)(Vf + 819200);       // 100*25600
    float*  proto= attb + 2560000;              // 5*25600
    float*  distb= proto + 128000;              // 375
    // total ~31 MB

    hipMemsetAsync(Qf, 0, 3276800 * sizeof(ushort), stream);
    hipMemsetAsync(Kf, 0,  819200 * sizeof(ushort), stream);
    hipMemsetAsync(Vf, 0,  819200 * sizeof(ushort), stream);

    k_build_src<<<1, 128, 0, stream>>>(target, src_idx);
    k_make_cat<<<NTOT, 256, 0, stream>>>(input, src_idx, catX);
    k_prep_wvo<<<129, 128, 0, stream>>>(Wv, bv, Wo, Wvo, bvo);

    k_gemm_qk<<<(NTOT * TT * VV + 63) / 64, 256, 0, stream>>>(catX, Wq, bq, Qf, NTOT * TT * VV);
    k_gemm_qk<<<(NP * TT * VV + 63) / 64, 256, 0, stream>>>(catX + (size_t)NQ * ROW, Wk, bk, Kf, NP * TT * VV);
    k_gemm_vo<<<(NP * TT * VV + 63) / 64, 256, 0, stream>>>(catX + (size_t)NQ * ROW, Wvo, bvo, Vf, NP * TT * VV);

    k_attn_mfma<<<NTOT * TT, 256, 0, stream>>>(Qf, Kf, Vf, catX, bo, ln_g, ln_b, attb);

    k_proto<<<NCLS, 256, 0, stream>>>(attb, proto);
    k_dist<<<NQ, 256, 0, stream>>>(attb, proto, distb);
    k_loss<<<1, 128, 0, stream>>>(distb, out);
}

// Round 3
// 237.910 us; speedup vs baseline: 3.6540x; 1.5156x over previous
//
#include <hip/hip_runtime.h>
#include <math.h>

// Problem constants (fixed by reference setup_inputs)
#define NTOT 100
#define NQ   75
#define NP   25
#define CC   128
#define TT   8
#define VV   25
#define NCLS 5
#define NSUP 5
#define NQRY 15
#define ROW  (TT*VV*CC)   // 25600 floats per sample
#define TILE (VV*CC)      // 3200 floats per (n,t)
#define ROWS_Q 20000      // all tv-rows
#define ROWS_S 5000       // support tv-rows
#define RB_Q 625          // 20000/32
#define RB_S 157          // ceil(5000/32)

typedef __attribute__((ext_vector_type(8))) short short8;
typedef __attribute__((ext_vector_type(16))) float f32x16;

__device__ __forceinline__ ushort f2bf(float f) {
    uint u = __float_as_uint(f);
    u += 0x7FFFu + ((u >> 16) & 1u);   // RNE
    return (ushort)(u >> 16);
}

// ============ kernel 1: prep ============
// blocks 0..99  : rank-sort (inline) + gather sample -> catX fp32 + bf16 A-frags
// blocks 100..103: weight -> bf16 B-frags (Wq,Wk,Wv,Wo); 103 also zeros supp pad
// block 104     : zero proto + out
__global__ __launch_bounds__(256) void k_prep(
    const float* __restrict__ input, const int* __restrict__ target,
    const float* __restrict__ Wq, const float* __restrict__ Wk,
    const float* __restrict__ Wv, const float* __restrict__ Wo,
    ushort* __restrict__ catQbf, ushort* __restrict__ catSbf,
    ushort* __restrict__ Wfrag, float* __restrict__ catX,
    float* __restrict__ proto, float* __restrict__ out) {
    __shared__ float smp[200 * 129];   // [tv][c], pad 129 -> conflict-free both ways
    __shared__ int targ[NTOT];
    __shared__ int order[NTOT];
    int b = blockIdx.x, tid = threadIdx.x;

    if (b < 100) {
        if (tid < NTOT) targ[tid] = target[tid];
        __syncthreads();
        if (tid < NTOT) {
            int ti = targ[tid], rank = 0;
            for (int j = 0; j < NTOT; ++j) {
                int tj = targ[j];
                rank += (tj < ti) || (tj == ti && j < tid);
            }
            order[rank] = tid;
        }
        __syncthreads();
        int n = b, src;
        if (n < NQ) { int m = n / NQRY, q = n - m * NQRY; src = order[m * 20 + NSUP + q]; }
        else        { int i = n - NQ; int m = i / NSUP, s = i - m * NSUP; src = order[m * 20 + s]; }

        const float* in = input + (size_t)src * ROW;
        for (int idx = tid; idx < ROW; idx += 256) {
            int c = idx / 200, tv = idx - c * 200;       // idx = c*200 + tv (coalesced read)
            smp[tv * 129 + c] = in[idx];
        }
        __syncthreads();
        // catX fp32 (coalesced write, conflict-free LDS read)
        float* cx = catX + (size_t)n * ROW;
        for (int e = tid; e < ROW; e += 256)
            cx[e] = smp[(e >> 7) * 129 + (e & 127)];
        // bf16 A-frag writes: o = k8*200 + tv (lanes: consecutive tv -> coalesced stores)
        bool isSup = (n >= NQ);
        for (int o = tid; o < 3200; o += 256) {
            int k8 = o / 200, tv = o - k8 * 200;
            int base = tv * 129 + k8 * 8;
            uint4 pk;
            pk.x = (uint)f2bf(smp[base+0]) | ((uint)f2bf(smp[base+1]) << 16);
            pk.y = (uint)f2bf(smp[base+2]) | ((uint)f2bf(smp[base+3]) << 16);
            pk.z = (uint)f2bf(smp[base+4]) | ((uint)f2bf(smp[base+5]) << 16);
            pk.w = (uint)f2bf(smp[base+6]) | ((uint)f2bf(smp[base+7]) << 16);
            int row = n * 200 + tv;
            size_t dst = (((size_t)(row >> 5) * 8 + (k8 >> 1)) * 64 + ((row & 31) + 32 * (k8 & 1))) * 8;
            *(uint4*)(catQbf + dst) = pk;
            if (isSup) {
                int r2 = (n - NQ) * 200 + tv;
                size_t dst2 = (((size_t)(r2 >> 5) * 8 + (k8 >> 1)) * 64 + ((r2 & 31) + 32 * (k8 & 1))) * 8;
                *(uint4*)(catSbf + dst2) = pk;
            }
        }
    } else if (b < 104) {
        const float* W = (b == 100) ? Wq : (b == 101) ? Wk : (b == 102) ? Wv : Wo;
        ushort* dstW = Wfrag + (size_t)(b - 100) * 16384;
        for (int o = tid; o < 2048; o += 256) {   // o = k8*128 + c (c fastest -> coalesced)
            int k8 = o >> 7, c = o & 127;
            uint4 pk;
            float f0 = W[(k8*8+0)*128 + c], f1 = W[(k8*8+1)*128 + c];
            float f2 = W[(k8*8+2)*128 + c], f3 = W[(k8*8+3)*128 + c];
            float f4 = W[(k8*8+4)*128 + c], f5 = W[(k8*8+5)*128 + c];
            float f6 = W[(k8*8+6)*128 + c], f7 = W[(k8*8+7)*128 + c];
            pk.x = (uint)f2bf(f0) | ((uint)f2bf(f1) << 16);
            pk.y = (uint)f2bf(f2) | ((uint)f2bf(f3) << 16);
            pk.z = (uint)f2bf(f4) | ((uint)f2bf(f5) << 16);
            pk.w = (uint)f2bf(f6) | ((uint)f2bf(f7) << 16);
            size_t dst = ((size_t)((c >> 5) * 8 + (k8 >> 1)) * 64 + ((c & 31) + 32 * (k8 & 1))) * 8;
            *(uint4*)(dstW + dst) = pk;
        }
        if (b == 103) {
            // zero invalid lanes of supp rowblk 156 (rows 5000..5023)
            uint4 z = make_uint4(0, 0, 0, 0);
            for (int o = tid; o < 512; o += 256) {
                int ks = o >> 6, l = o & 63;
                if ((l & 31) >= 8)
                    *(uint4*)(catSbf + (((size_t)156 * 8 + ks) * 64 + l) * 8) = z;
            }
        }
    } else {
        for (int i = tid; i < NCLS * ROW; i += 256) proto[i] = 0.f;
        if (tid < 2) out[tid] = 0.f;
    }
}

// ============ kernel 2: projections via MFMA ============
// blocks 0..156: Q = cat@Wq+bq (rowblks 0..624)
// blocks 157..196: K = supp@Wk+bk (rowblks 0..156)
// blocks 197..236: V two-stage: Vt = supp@Wv+bv (LDS), Vo = Vt@Wo -> VO frags
__global__ __launch_bounds__(256) void k_proj(
    const ushort* __restrict__ catQbf, const ushort* __restrict__ catSbf,
    const ushort* __restrict__ Wfrag, const float* __restrict__ bq,
    const float* __restrict__ bk, const float* __restrict__ bv,
    ushort* __restrict__ Qf, ushort* __restrict__ Kf, ushort* __restrict__ Vf) {
    __shared__ ushort Vt[128 * 136];   // pad 136 (16B-aligned rows)
    int b = blockIdx.x, tid = threadIdx.x;
    int w = tid >> 6, lane = tid & 63;
    int typ, rb0, nrb;
    if (b < 157)      { typ = 0; rb0 = b * 4;         nrb = RB_Q; }
    else if (b < 197) { typ = 1; rb0 = (b - 157) * 4; nrb = RB_S; }
    else              { typ = 2; rb0 = (b - 197) * 4; nrb = RB_S; }
    int rowblk = rb0 + w;
    bool act = rowblk < nrb;
    const ushort* src = (typ == 0) ? catQbf : catSbf;
    const ushort* Wf = Wfrag + (size_t)typ * 16384;
    const float* bias = (typ == 0) ? bq : (typ == 1) ? bk : bv;
    int rlimit = (typ == 0) ? ROWS_Q : ROWS_S;

    short8 af[8];
    if (act) {
        const ushort* ap = src + (size_t)rowblk * 4096 + lane * 8;
        #pragma unroll
        for (int ks = 0; ks < 8; ++ks) af[ks] = *(const short8*)(ap + ks * 512);
    }
    #pragma unroll
    for (int ct = 0; ct < 4; ++ct) {
        f32x16 Cm;
        #pragma unroll
        for (int r = 0; r < 16; ++r) Cm[r] = 0.f;
        if (act) {
            const ushort* bp = Wf + (size_t)(ct * 8) * 512 + lane * 8;
            #pragma unroll
            for (int ks = 0; ks < 8; ++ks) {
                short8 bf_ = *(const short8*)(bp + ks * 512);
                Cm = __builtin_amdgcn_mfma_f32_32x32x16_bf16(af[ks], bf_, Cm, 0, 0, 0);
            }
            float bcol = bias[ct * 32 + (lane & 31)];
            if (typ <= 1) {
                ushort* dstB = (typ == 0) ? Qf : Kf;
                #pragma unroll
                for (int r = 0; r < 16; ++r) {
                    int row = rowblk * 32 + (r & 3) + 8 * (r >> 2) + 4 * (lane >> 5);
                    if (row < rlimit) {
                        int c = ct * 32 + (lane & 31);
                        int st = row / 25, vv = row - st * 25;
                        size_t dst = (((size_t)st * 8 + (c >> 4)) * 64 + (vv + 32 * ((c >> 3) & 1))) * 8 + (c & 7);
                        dstB[dst] = f2bf(Cm[r] + bcol);
                    }
                }
            } else {
                #pragma unroll
                for (int r = 0; r < 16; ++r) {
                    int lrow = w * 32 + (r & 3) + 8 * (r >> 2) + 4 * (lane >> 5);
                    Vt[lrow * 136 + ct * 32 + (lane & 31)] = f2bf(Cm[r] + bcol);
                }
            }
        }
    }
    if (typ == 2) {
        __syncthreads();
        const ushort* WoF = Wfrag + (size_t)3 * 16384;
        short8 a2[8];
        if (act) {
            #pragma unroll
            for (int ks = 0; ks < 8; ++ks)
                a2[ks] = *(const short8*)(Vt + (w * 32 + (lane & 31)) * 136 + ks * 16 + (lane >> 5) * 8);
        }
        #pragma unroll
        for (int ct = 0; ct < 4; ++ct) {
            if (act) {
                f32x16 Cm;
                #pragma unroll
                for (int r = 0; r < 16; ++r) Cm[r] = 0.f;
                const ushort* bp = WoF + (size_t)(ct * 8) * 512 + lane * 8;
                #pragma unroll
                for (int ks = 0; ks < 8; ++ks) {
                    short8 bf_ = *(const short8*)(bp + ks * 512);
                    Cm = __builtin_amdgcn_mfma_f32_32x32x16_bf16(a2[ks], bf_, Cm, 0, 0, 0);
                }
                #pragma unroll
                for (int r = 0; r < 16; ++r) {
                    int row = rowblk * 32 + (r & 3) + 8 * (r >> 2) + 4 * (lane >> 5);
                    if (row < ROWS_S) {
                        int c = ct * 32 + (lane & 31);
                        int tile = row / 25, vv = row - tile * 25;
                        size_t dst = ((((size_t)tile * 4 + ct) * 2 + (vv >> 4)) * 64
                                      + ((c & 31) + 32 * ((vv & 15) >> 3))) * 8 + (vv & 7);
                        Vf[dst] = f2bf(Cm[r]);
                    }
                }
            }
        }
    }
}

// ============ kernel 3: MFMA fused attention + residual + LN ============
// block per (n,t,half-of-m); emits RAW LN sums (g,b,1/25 folded downstream).
// Query blocks write att0/att1; support blocks atomicAdd *0.2 into proto.
__global__ __launch_bounds__(256, 2) void k_attn(
    const ushort* __restrict__ Qf, const ushort* __restrict__ Kf,
    const ushort* __restrict__ Vf, const float* __restrict__ catX,
    const float* __restrict__ bo, float* __restrict__ att0,
    float* __restrict__ att1, float* __restrict__ proto) {
    __shared__ float catb[25][132];
    __shared__ ushort pfrag[4][2][64][8];
    __shared__ float red[64][68];

    int pair = blockIdx.x >> 1;    // n*8 + t
    int h = blockIdx.x & 1;
    int n = pair >> 3, t = pair & 7;
    int tid = threadIdx.x;
    int wv = tid >> 6, lane = tid & 63;
    int q = lane & 31, half = lane >> 5;

    size_t base = (size_t)pair * TILE;
    for (int idx = tid; idx < TILE; idx += 256) {
        int qq = idx >> 7, c = idx & 127;
        catb[qq][c] = catX[base + idx] + bo[c];
    }
    // zero the wave's P-frag (key>=25 slots stay 0 -> garbage V cols annihilated)
    *(uint4*)&pfrag[wv][0][lane][0] = make_uint4(0, 0, 0, 0);
    *(uint4*)&pfrag[wv][1][lane][0] = make_uint4(0, 0, 0, 0);

    short8 qf[8];
    {
        const ushort* qp = Qf + (size_t)pair * 4096 + lane * 8;
        #pragma unroll
        for (int ks = 0; ks < 8; ++ks) qf[ks] = *(const short8*)(qp + ks * 512);
    }
    __syncthreads();

    int qc = q < 25 ? q : 24;
    float attsum[64];
    #pragma unroll
    for (int i = 0; i < 64; ++i) attsum[i] = 0.f;

    const float CEXP = (float)(1.4426950408889634 * 0.08838834764831845);

    int mEnd = h ? 25 : 13;
    for (int m = h * 13 + wv; m < mEnd; m += 4) {
        const ushort* kp = Kf + ((size_t)(m * 8 + t)) * 4096 + lane * 8;
        short8 kf[8];
        #pragma unroll
        for (int ks = 0; ks < 8; ++ks) kf[ks] = *(const short8*)(kp + ks * 512);
        f32x16 S;
        #pragma unroll
        for (int r = 0; r < 16; ++r) S[r] = 0.f;
        #pragma unroll
        for (int ks = 0; ks < 8; ++ks)
            S = __builtin_amdgcn_mfma_f32_32x32x16_bf16(kf[ks], qf[ks], S, 0, 0, 0);

        float p[16], mx = -3e38f;
        #pragma unroll
        for (int r = 0; r < 16; ++r) {
            int key = (r & 3) + 8 * (r >> 2) + 4 * half;
            float v = (key < 25) ? S[r] : -3e38f;
            p[r] = v; mx = fmaxf(mx, v);
        }
        mx = fmaxf(mx, __shfl_xor(mx, 32));
        float sum = 0.f;
        #pragma unroll
        for (int r = 0; r < 16; ++r) { p[r] = exp2f((p[r] - mx) * CEXP); sum += p[r]; }
        sum += __shfl_xor(sum, 32);
        float inv = 1.f / sum;

        #pragma unroll
        for (int r = 0; r < 16; ++r) {
            int key = (r & 3) + 8 * (r >> 2) + 4 * half;
            if (key < 25)
                pfrag[wv][key >> 4][q + 32 * ((key >> 3) & 1)][key & 7] = f2bf(p[r] * inv);
        }
        short8 pb0 = *(const short8*)&pfrag[wv][0][lane][0];
        short8 pb1 = *(const short8*)&pfrag[wv][1][lane][0];

        const ushort* vp = Vf + ((size_t)(m * 8 + t)) * 4096 + lane * 8;
        f32x16 ctx[4];
        #pragma unroll
        for (int mt = 0; mt < 4; ++mt) {
            short8 v0 = *(const short8*)(vp + mt * 1024);
            short8 v1 = *(const short8*)(vp + mt * 1024 + 512);
            f32x16 c;
            #pragma unroll
            for (int r = 0; r < 16; ++r) c[r] = 0.f;
            c = __builtin_amdgcn_mfma_f32_32x32x16_bf16(v0, pb0, c, 0, 0, 0);
            c = __builtin_amdgcn_mfma_f32_32x32x16_bf16(v1, pb1, c, 0, 0, 0);
            ctx[mt] = c;
        }

        float s1 = 0.f, s2 = 0.f;
        #pragma unroll
        for (int mt = 0; mt < 4; ++mt) {
            #pragma unroll
            for (int r = 0; r < 16; ++r) {
                int c = mt * 32 + (r & 3) + 8 * (r >> 2) + 4 * half;
                float xv = ctx[mt][r] + catb[qc][c];
                ctx[mt][r] = xv;
                s1 += xv; s2 += xv * xv;
            }
        }
        s1 += __shfl_xor(s1, 32); s2 += __shfl_xor(s2, 32);
        float mu = s1 * (1.f / 128.f);
        float var = s2 * (1.f / 128.f) - mu * mu;
        var = fmaxf(var, 0.f);
        float rs = rsqrtf(var + 1e-12f);
        #pragma unroll
        for (int mt = 0; mt < 4; ++mt) {
            #pragma unroll
            for (int r = 0; r < 16; ++r)
                attsum[mt * 16 + r] += (ctx[mt][r] - mu) * rs;
        }
    }

    __syncthreads();
    if (wv == 0) {
        #pragma unroll
        for (int i = 0; i < 64; ++i) red[lane][i] = attsum[i];
    }
    __syncthreads();
    if (wv == 1) {
        #pragma unroll
        for (int i = 0; i < 64; ++i) red[lane][i] += attsum[i];
    }
    __syncthreads();
    if (wv == 2) {
        #pragma unroll
        for (int i = 0; i < 64; ++i) red[lane][i] += attsum[i];
    }
    __syncthreads();
    if (wv == 3 && q < 25) {
        if (n < NQ) {
            float* ah = h ? att1 : att0;
            #pragma unroll
            for (int mt = 0; mt < 4; ++mt) {
                #pragma unroll
                for (int r = 0; r < 16; ++r) {
                    int c = mt * 32 + (r & 3) + 8 * (r >> 2) + 4 * half;
                    ah[base + q * 128 + c] = red[lane][mt * 16 + r] + attsum[mt * 16 + r];
                }
            }
        } else {
            int cls = (n - NQ) / NSUP;
            float* pp = proto + (size_t)cls * ROW + t * TILE;
            #pragma unroll
            for (int mt = 0; mt < 4; ++mt) {
                #pragma unroll
                for (int r = 0; r < 16; ++r) {
                    int c = mt * 32 + (r & 3) + 8 * (r >> 2) + 4 * half;
                    float v = (red[lane][mt * 16 + r] + attsum[mt * 16 + r]) * 0.2f;
                    atomicAdd(&pp[q * 128 + c], v);
                }
            }
        }
    }
}

// ============ kernel 4: fused distance + log-softmax loss/acc ============
// dist_j = sum_c g_c^2/625 * (S_q - Pbar_j)^2 ; atomicAdd loss/acc into out.
__global__ __launch_bounds__(256) void k_dist_loss(
    const float* __restrict__ att0, const float* __restrict__ att1,
    const float* __restrict__ proto, const float* __restrict__ ln_g,
    float* __restrict__ out) {
    int i = blockIdx.x;   // query 0..74
    const float* a0 = att0 + (size_t)i * ROW;
    const float* a1 = att1 + (size_t)i * ROW;
    float d[5] = {0.f, 0.f, 0.f, 0.f, 0.f};
    for (int e = threadIdx.x; e < ROW; e += 256) {
        float g = ln_g[e & 127];
        float wgt = g * g * (1.f / 625.f);
        float av = a0[e] + a1[e];
        #pragma unroll
        for (int j = 0; j < 5; ++j) {
            float diff = av - proto[(size_t)j * ROW + e];
            d[j] += wgt * diff * diff;
        }
    }
    __shared__ float part[4][5];
    int lane = threadIdx.x & 63, wv = threadIdx.x >> 6;
    #pragma unroll
    for (int j = 0; j < 5; ++j) {
        #pragma unroll
        for (int msk = 32; msk >= 1; msk >>= 1) d[j] += __shfl_xor(d[j], msk);
    }
    if (lane == 0) {
        #pragma unroll
        for (int j = 0; j < 5; ++j) part[wv][j] = d[j];
    }
    __syncthreads();
    if (threadIdx.x == 0) {
        float dd[5];
        #pragma unroll
        for (int j = 0; j < 5; ++j)
            dd[j] = part[0][j] + part[1][j] + part[2][j] + part[3][j];
        int cls = i / NQRY;
        float mind = dd[0];
        int best = 0;
        #pragma unroll
        for (int j = 1; j < 5; ++j) {
            if (dd[j] < mind) mind = dd[j];
            if (dd[j] < dd[best]) best = j;   // first-min == argmax(-d)
        }
        float sume = 0.f;
        #pragma unroll
        for (int j = 0; j < 5; ++j) sume += expf(mind - dd[j]);
        float lse = logf(sume) - mind;
        float li = dd[cls] + lse;
        float ok = (best == cls) ? 1.f : 0.f;
        atomicAdd(&out[0], li * (1.f / 75.f));
        atomicAdd(&out[1], ok * (1.f / 75.f));
    }
}

extern "C" void kernel_launch(void* const* d_in, const int* in_sizes, int n_in,
                              void* d_out, int out_size, void* d_ws, size_t ws_size,
                              hipStream_t stream) {
    const float* input = (const float*)d_in[0];
    const float* Wq   = (const float*)d_in[1];
    const float* bq   = (const float*)d_in[2];
    const float* Wk   = (const float*)d_in[3];
    const float* bk   = (const float*)d_in[4];
    const float* Wv   = (const float*)d_in[5];
    const float* bv   = (const float*)d_in[6];
    const float* Wo   = (const float*)d_in[7];
    const float* bo   = (const float*)d_in[8];
    const float* ln_g = (const float*)d_in[9];
    const float* ln_b = (const float*)d_in[10];  // cancels in the distance
    const int* target = (const int*)d_in[11];
    float* out = (float*)d_out;
    (void)ln_b;

    float* ws = (float*)d_ws;
    // Overlay region A (dead after k_proj, reused as att0):
    //   catQbf 2,560,000 u16 | catSbf 643,072 u16 | Wfrag 65,536 u16  (= 6.54 MB)
    //   att0: 600*3200 fp32 = 7.68 MB  -> region A sized 1,920,000 floats
    float*  att0   = ws;
    ushort* catQbf = (ushort*)ws;
    ushort* catSbf = catQbf + (size_t)RB_Q * 4096;           // 2,560,000
    ushort* Wfrag  = catSbf + (size_t)RB_S * 4096;           // +643,072
    ushort* Qf   = (ushort*)(ws + 1920000);                  // 800*4096 u16
    ushort* Kf   = Qf + 3276800;                             // 200*4096
    ushort* Vf   = Kf + 819200;                              // 200*4096
    float*  catX = ws + 1920000 + 1638400 + 409600 + 409600; // 100*25600 fp32
    float*  proto= catX + 2560000;                           // 5*25600
    float*  att1 = proto + 128000;                           // 600*3200
    // total = 8,985,600 floats = 35.9 MB

    k_prep<<<105, 256, 0, stream>>>(input, target, Wq, Wk, Wv, Wo,
                                    catQbf, catSbf, Wfrag, catX, proto, out);
    k_proj<<<237, 256, 0, stream>>>(catQbf, catSbf, Wfrag, bq, bk, bv, Qf, Kf, Vf);
    k_attn<<<1600, 256, 0, stream>>>(Qf, Kf, Vf, catX, bo, att0, att1, proto);
    k_dist_loss<<<75, 256, 0, stream>>>(att0, att1, proto, ln_g, out);
}